// Round 10
// baseline (169.848 us; speedup 1.0000x reference)
//
#include <hip/hip_runtime.h>
#include <math.h>

// Density-Aware Chamfer Loss, B=4, N=8192, fp32 3D points.
//
// Round-10 model: hot kernel is at the SUSTAINED VALU roofline (~60% of 2.4GHz
// spec under full fp32 load; matches learn_hip m07's 103/157 TF). So: fewer
// instructions per pair. Hot loop drops index tracking: per 2 targets,
// 6 v_fma + 1 v_min3_f32 = 3.5 VALU/pair (was 6). Slots hold per-slice MIN
// DISTANCE (float, expanded form k = |t|^2 - 2q.t). Index recovered in the
// merge kernel: argmin slice via strict-< scan (ties -> lowest slice), then a
// wave-cooperative re-scan of the 128-target winning slice (coalesced;
// packed-u32 butterfly argmin, ties -> lowest j) = 1/64 of phase-1 work.
// Combined tie-break = global first-min, matching jnp.argmin.
//
// count+loss fused into one kernel with a spin barrier over its 256 blocks
// (1 block/CU -> all co-resident, no deadlock; arrival counter zeroed by
// partial, ordered by the kernel boundary).
//
// ws: [slot NSLICE*2BN f32 (16.8MB)][cnt 2BN int][arrive 1 int]
// Dispatches: partial(+zero cnt,arrive) -> countloss.   (2 total)

#define NPTS   8192
#define QPT    16                   // queries per thread
#define BLK    256
#define TSL    128                  // targets per slice (2KB LDS as float4)
#define NSLICE (NPTS / TSL)         // 64
#define QCH    (NPTS / (QPT * BLK)) // 2

__global__ __launch_bounds__(BLK, 4) void dacl_partial(
    const float* __restrict__ gts, const float* __restrict__ preds,
    float* __restrict__ slot, int* __restrict__ cnt, int* __restrict__ arrive,
    int B, int N)
{
    const int bz  = blockIdx.z;      // dir*B + b
    const int dir = bz / B;
    const int b   = bz - dir * B;
    const int total = 2 * B * N;

    // fold cnt/arrive zeroing in (first read by dacl_countloss -> ordered)
    if (blockIdx.y == 0) {
        const int nblk = QCH * 2 * B;             // 16 blocks share the job
        const int blk  = blockIdx.x + QCH * bz;
        const int per  = total / nblk;            // 4096
        int* p = cnt + blk * per;
        for (int k = threadIdx.x; k < per; k += BLK) p[k] = 0;
        if (blk == 0 && threadIdx.x == 0) *arrive = 0;
    }

    const float* __restrict__ q = (dir == 0 ? gts : preds) + (size_t)b * N * 3;
    const float* __restrict__ t = (dir == 0 ? preds : gts) + (size_t)b * N * 3;

    __shared__ float4 tile[TSL];
    const int tbase = blockIdx.y * TSL;

    if (threadIdx.x < TSL) {
        const int j = tbase + threadIdx.x;
        const float tx = t[3 * j], ty = t[3 * j + 1], tz = t[3 * j + 2];
        tile[threadIdx.x] = make_float4(tx, ty, tz, tx * tx + ty * ty + tz * tz);
    }
    __syncthreads();

    float m2x[QPT], m2y[QPT], m2z[QPT], best[QPT];
    const int qbase = blockIdx.x * (QPT * BLK);
    #pragma unroll
    for (int u = 0; u < QPT; ++u) {
        const int i = qbase + u * BLK + threadIdx.x;   // coalesced across lanes
        m2x[u]  = -2.0f * q[3 * i];
        m2y[u]  = -2.0f * q[3 * i + 1];
        m2z[u]  = -2.0f * q[3 * i + 2];
        best[u] = 3.402823466e38f;
    }

    // hot loop: per 2 targets: 2 ds_read_b128 + QPT*(6 fma + 1 min3) = 3.5/pair
    #pragma unroll 2
    for (int j = 0; j < TSL; j += 2) {
        const float4 a = tile[j];
        const float4 c = tile[j + 1];
        #pragma unroll
        for (int u = 0; u < QPT; ++u) {
            const float k1 = fmaf(m2x[u], a.x,
                             fmaf(m2y[u], a.y,
                             fmaf(m2z[u], a.z, a.w)));
            const float k2 = fmaf(m2x[u], c.x,
                             fmaf(m2y[u], c.y,
                             fmaf(m2z[u], c.z, c.w)));
            best[u] = fminf(fminf(k1, k2), best[u]);     // -> v_min3_f32
        }
    }

    const size_t obase = (size_t)bz * N;
    #pragma unroll
    for (int u = 0; u < QPT; ++u) {
        const int i = qbase + u * BLK + threadIdx.x;
        slot[(size_t)blockIdx.y * total + obase + i] = best[u];  // coalesced store
    }
}

__global__ __launch_bounds__(BLK) void dacl_countloss(
    const float* __restrict__ gts, const float* __restrict__ preds,
    const float* __restrict__ slot, int* __restrict__ cnt,
    int* __restrict__ arrive, float* __restrict__ out, int out_size,
    int B, int N)
{
    const int g    = blockIdx.x * BLK + threadIdx.x;     // query id
    const int bz   = g / N;                              // block-uniform (N%BLK==0)
    const int dir  = bz / B;
    const int b    = bz - dir * B;
    const int iq   = g - bz * N;
    const int lane = threadIdx.x & 63;
    const int total = 2 * B * N;

    if (blockIdx.x == 0 && threadIdx.x < out_size) out[threadIdx.x] = 0.0f;

    const float* __restrict__ q = (dir == 0 ? gts : preds) + (size_t)b * N * 3;
    const float* __restrict__ t = (dir == 0 ? preds : gts) + (size_t)b * N * 3;

    // A1: cross-slice min, strict < ascending -> lowest slice wins ties
    float m = slot[g];
    int sstar = 0;
    #pragma unroll 8
    for (int s = 1; s < NSLICE; ++s) {
        const float v = slot[(size_t)s * total + g];     // coalesced per row
        if (v < m) { m = v; sstar = s; }
    }

    const float qx = q[3 * iq], qy = q[3 * iq + 1], qz = q[3 * iq + 2];
    const float ax = -2.0f * qx, ay = -2.0f * qy, az = -2.0f * qz;

    // A2: wave-cooperative re-scan of each query's winning slice (128 targets,
    // 2 per lane, coalesced). Packed key: (monotone(k) & ~0xFF) | j_local ->
    // u32 min = first-min tie-break within slice.
    unsigned int res = 0;
    for (int qq = 0; qq < 64; ++qq) {
        const int   s   = __shfl(sstar, qq, 64);
        const float bx  = __shfl(ax, qq, 64);
        const float by  = __shfl(ay, qq, 64);
        const float bzv = __shfl(az, qq, 64);
        const float* tb = t + 3 * (s * TSL);
        float tx = tb[3 * lane], ty = tb[3 * lane + 1], tz = tb[3 * lane + 2];
        float tw = fmaf(tx, tx, fmaf(ty, ty, tz * tz));
        const float k1 = fmaf(bx, tx, fmaf(by, ty, fmaf(bzv, tz, tw)));
        tx = tb[3 * (lane + 64)]; ty = tb[3 * (lane + 64) + 1]; tz = tb[3 * (lane + 64) + 2];
        tw = fmaf(tx, tx, fmaf(ty, ty, tz * tz));
        const float k2 = fmaf(bx, tx, fmaf(by, ty, fmaf(bzv, tz, tw)));
        unsigned int u1 = __float_as_uint(k1);
        u1 = ((int)u1 < 0) ? ~u1 : (u1 | 0x80000000u);
        unsigned int u2 = __float_as_uint(k2);
        u2 = ((int)u2 < 0) ? ~u2 : (u2 | 0x80000000u);
        unsigned int kk = min((u1 & 0xFFFFFF00u) | (unsigned int)lane,
                              (u2 & 0xFFFFFF00u) | (unsigned int)(lane + 64));
        #pragma unroll
        for (int off = 1; off < 64; off <<= 1)
            kk = min(kk, (unsigned int)__shfl_xor((int)kk, off, 64));
        if (lane == qq) res = kk;                        // lane qq owns query qq
    }
    const int idxg = sstar * TSL + (int)(res & 0xFFu);   // global NN index
    atomicAdd(&cnt[bz * N + idxg], 1);

    // grid barrier: 256 blocks = 1/CU, all co-resident -> spin is deadlock-free
    __threadfence();
    __syncthreads();
    if (threadIdx.x == 0) {
        __hip_atomic_fetch_add(arrive, 1, __ATOMIC_ACQ_REL, __HIP_MEMORY_SCOPE_AGENT);
        while (__hip_atomic_load(arrive, __ATOMIC_ACQUIRE, __HIP_MEMORY_SCOPE_AGENT)
               < (int)gridDim.x)
            __builtin_amdgcn_s_sleep(8);
    }
    __syncthreads();

    // B: loss — exact distance recomputed like the reference's gather form
    const float dx = qx - t[3 * idxg];
    const float dy = qy - t[3 * idxg + 1];
    const float dz = qz - t[3 * idxg + 2];
    const float d  = dx * dx + dy * dy + dz * dz;
    const int   c  = __hip_atomic_load(&cnt[bz * N + idxg], __ATOMIC_RELAXED,
                                       __HIP_MEMORY_SCOPE_AGENT);
    float sv = 1.0f - expf(-d) / ((float)c + 1e-6f);     // count^1, frac = 1
    for (int off = 32; off > 0; off >>= 1) sv += __shfl_down(sv, off, 64);
    if (lane == 0)
        atomicAdd(&out[b], sv / (2.0f * (float)N));      // (mean1+mean2)/2
}

extern "C" void kernel_launch(void* const* d_in, const int* in_sizes, int n_in,
                              void* d_out, int out_size, void* d_ws, size_t ws_size,
                              hipStream_t stream)
{
    const float* gts   = (const float*)d_in[0];
    const float* preds = (const float*)d_in[1];

    const int N = NPTS;
    const int B = in_sizes[0] / (N * 3);                 // = 4

    const size_t nTot = (size_t)2 * B * N;               // 65536 queries
    float* slot   = (float*)d_ws;                        // NSLICE x nTot (16.8MB)
    int*   cnt    = (int*)((char*)d_ws + (size_t)NSLICE * nTot * sizeof(float));
    int*   arrive = (int*)(cnt + nTot);

    dim3 gA(QCH, NSLICE, B * 2);                         // 2 x 64 x 8 = 1024 blocks
    dacl_partial<<<gA, BLK, 0, stream>>>(gts, preds, slot, cnt, arrive, B, N);

    dacl_countloss<<<(int)(nTot / BLK), BLK, 0, stream>>>(
        gts, preds, slot, cnt, arrive, (float*)d_out, out_size, B, N);
}

// Round 11
// 130.174 us; speedup vs baseline: 1.3048x; 1.3048x over previous
//
#include <hip/hip_runtime.h>
#include <math.h>

// Density-Aware Chamfer Loss, B=4, N=8192, fp32 3D points.
//
// Round-11: move the distance matrix off the VALU (empirical floor ~3 G
// pair/us across r5-r10) onto the matrix cores. One v_mfma_f32_32x32x16_bf16
// computes a 32x32 tile of EXACT-form distances via K=13 (of 16) slots:
//   k0-2: thi . (-2 qhi)     k3-5: thi . (-2 qlo)    k6-8: tlo . (-2 qhi)
//   k9:   |t|^2_hi . 1       k10:  |t|^2_lo . 1
//   k11:  1 . |q|^2_hi       k12:  1 . |q|^2_lo      k13-15: 0
// acc = d + O(2e-4) (missing tlo.qlo only) — 5x tighter than the 13-bit
// truncation already validated in r8 (absmax 2e-3 vs 8.4e-3 threshold).
// Per-lane VALU: 9-instr min3 tree per 16 pairs (~0.6 op/pair vs 3.5 in r10).
// Row-mapping robustness: per-128-target-group MIN is invariant to the C/D
// row permutation and to any common A/B k-permutation; only col=lane&31
// (HW-verified m74/m101) is load-bearing. Exact index recovered by a separate
// rescan of the winning group; exact distance recomputed for the loss.
//
// ws: [slot 64grp x 2BN f32 (16.8MB, r8-proven)][idxArr 2BN][cnt 2BN]
// Dispatches: partial(+zero cnt) -> merge(+zero out) -> loss.   (3 total)

#define NPTS   8192
#define BLK    256
#define QPB    128                  // queries per block (4 waves x 32)
#define TPS    2048                 // targets per slice
#define TILES  (TPS / 32)           // 64 MFMA tiles per slice
#define NSLICE (NPTS / TPS)         // 4
#define QCH    (NPTS / QPB)         // 64
#define GRP    128                  // targets per slot group
#define NGRP   (NPTS / GRP)         // 64

typedef __attribute__((ext_vector_type(8)))  short short8;
typedef __attribute__((ext_vector_type(16))) float float16v;

__device__ inline void bsplit(float x, unsigned short& h, unsigned short& l) {
    const unsigned int u = __float_as_uint(x);
    const unsigned short hh = (unsigned short)(u >> 16);   // truncated bf16 hi
    const float lf = x - __uint_as_float((unsigned int)hh << 16);
    h = hh;
    l = (unsigned short)(__float_as_uint(lf) >> 16);       // bf16 lo
}

__global__ __launch_bounds__(BLK) void dacl_partial(
    const float* __restrict__ gts, const float* __restrict__ preds,
    float* __restrict__ slot, int* __restrict__ cnt, int B, int N)
{
    const int bz  = blockIdx.z;      // dir*B + b
    const int dir = bz / B;
    const int b   = bz - dir * B;
    const int total = 2 * B * N;

    // fold cnt zeroing in (first read by dacl_merge -> kernel boundary orders)
    if (blockIdx.y == 0) {
        const int per = total / (QCH * 2 * B);             // 128
        int* p = cnt + (blockIdx.x + QCH * bz) * per;
        for (int k = threadIdx.x; k < per; k += BLK) p[k] = 0;
    }

    const float* __restrict__ q = (dir == 0 ? gts : preds) + (size_t)b * N * 3;
    const float* __restrict__ t = (dir == 0 ? preds : gts) + (size_t)b * N * 3;

    __shared__ short8 frag[TILES * 64];                    // 64KB A-frags

    // stage+pack A-frags: 2048 targets, 8 per thread
    const int sbase = blockIdx.y * TPS;
    for (int rep = 0; rep < TPS / BLK; ++rep) {
        const int tgt = rep * BLK + threadIdx.x;
        const int j   = sbase + tgt;
        const float tx = t[3 * j], ty = t[3 * j + 1], tz = t[3 * j + 2];
        const float t2 = fmaf(tx, tx, fmaf(ty, ty, tz * tz));
        unsigned short hx, lx, hy, ly, hz, lz, h2, l2;
        bsplit(tx, hx, lx); bsplit(ty, hy, ly); bsplit(tz, hz, lz); bsplit(t2, h2, l2);
        union { short8 v; unsigned short s[8]; } k0, k1;
        k0.s[0]=hx; k0.s[1]=hy; k0.s[2]=hz; k0.s[3]=hx; k0.s[4]=hy; k0.s[5]=hz; k0.s[6]=lx; k0.s[7]=ly;
        k1.s[0]=lz; k1.s[1]=h2; k1.s[2]=l2; k1.s[3]=0x3F80; k1.s[4]=0x3F80; k1.s[5]=0; k1.s[6]=0; k1.s[7]=0;
        const int tile = tgt >> 5, row = tgt & 31;
        frag[tile * 64 + row]      = k0.v;                 // k-half 0 (lanes 0-31)
        frag[tile * 64 + 32 + row] = k1.v;                 // k-half 1 (lanes 32-63)
    }

    // B-frag: each wave owns 32 queries; lane&31 = query col, lane>>5 = k-half
    const int lane = threadIdx.x & 63;
    const int wave = threadIdx.x >> 6;
    const int qi   = blockIdx.x * QPB + wave * 32 + (lane & 31);
    const float qx = q[3 * qi], qy = q[3 * qi + 1], qz = q[3 * qi + 2];
    const float q2 = fmaf(qx, qx, fmaf(qy, qy, qz * qz));
    unsigned short shx, slx, shy, sly, shz, slz, h2q, l2q;
    bsplit(-2.0f * qx, shx, slx); bsplit(-2.0f * qy, shy, sly);
    bsplit(-2.0f * qz, shz, slz); bsplit(q2, h2q, l2q);
    union { short8 v; unsigned short s[8]; } bu;
    if ((lane >> 5) == 0) {
        bu.s[0]=shx; bu.s[1]=shy; bu.s[2]=shz; bu.s[3]=slx; bu.s[4]=sly; bu.s[5]=slz; bu.s[6]=shx; bu.s[7]=shy;
    } else {
        bu.s[0]=shz; bu.s[1]=0x3F80; bu.s[2]=0x3F80; bu.s[3]=h2q; bu.s[4]=l2q; bu.s[5]=0; bu.s[6]=0; bu.s[7]=0;
    }
    const short8 bfrag = bu.v;

    __syncthreads();

    const float16v zz = {0.f,0.f,0.f,0.f, 0.f,0.f,0.f,0.f,
                         0.f,0.f,0.f,0.f, 0.f,0.f,0.f,0.f};
    const size_t gq = (size_t)bz * N + qi;
    float gmin = 3.402823466e38f;

    // hot loop: 1 ds_read_b128 + 1 mfma + 9-op min3 tree per 1024 pairs
    #pragma unroll 2
    for (int tile = 0; tile < TILES; ++tile) {
        const short8 av = frag[tile * 64 + lane];
        float16v acc = __builtin_amdgcn_mfma_f32_32x32x16_bf16(av, bfrag, zz, 0, 0, 0);
        const float t0 = fminf(fminf(acc[0],  acc[1]),  acc[2]);
        const float t1 = fminf(fminf(acc[3],  acc[4]),  acc[5]);
        const float t2 = fminf(fminf(acc[6],  acc[7]),  acc[8]);
        const float t3 = fminf(fminf(acc[9],  acc[10]), acc[11]);
        const float t4 = fminf(fminf(acc[12], acc[13]), acc[14]);
        const float u0 = fminf(fminf(t0, t1), acc[15]);
        const float u1 = fminf(fminf(t2, t3), t4);
        gmin = fminf(gmin, fminf(u0, u1));
        if ((tile & 3) == 3) {                             // close a 128-target group
            const float o = fminf(gmin, __shfl_xor(gmin, 32, 64));  // both row-halves
            if (lane < 32)
                slot[(size_t)(blockIdx.y * (TILES / 4) + (tile >> 2)) * total + gq] = o;
            gmin = 3.402823466e38f;
        }
    }
}

// per-query: argmin group over approx slots, exact rescan of the 128-target
// winning group (sequential float4 loads -> MLP-covered), exact first-min idx
__global__ __launch_bounds__(256) void dacl_merge(
    const float* __restrict__ gts, const float* __restrict__ preds,
    const float* __restrict__ slot, int* __restrict__ idxArr,
    int* __restrict__ cnt, float* __restrict__ out, int out_size, int B, int N)
{
    const int g = blockIdx.x * 256 + threadIdx.x;
    if (blockIdx.x == 0 && threadIdx.x < out_size) out[threadIdx.x] = 0.0f;
    const int total = 2 * B * N;
    if (g >= total) return;
    const int bz = g / N, dir = bz / B, b = bz - dir * B;
    const int iq = g - bz * N;
    const float* __restrict__ q = (dir == 0 ? gts : preds) + (size_t)b * N * 3;
    const float* __restrict__ t = (dir == 0 ? preds : gts) + (size_t)b * N * 3;

    float m = slot[g];
    int gr = 0;
    #pragma unroll 8
    for (int s = 1; s < NGRP; ++s) {                       // strict < ascending
        const float v = slot[(size_t)s * total + g];       // coalesced row
        if (v < m) { m = v; gr = s; }
    }

    const float qx = q[3 * iq], qy = q[3 * iq + 1], qz = q[3 * iq + 2];
    const float4* __restrict__ tb4 = (const float4*)(t + (size_t)gr * GRP * 3);
    unsigned int best = 0xFFFFFFFFu;
    for (int c = 0; c < 8; ++c) {                          // 16 targets per chunk
        float f[48];
        #pragma unroll
        for (int j2 = 0; j2 < 12; ++j2) {
            const float4 v = tb4[c * 12 + j2];
            f[4 * j2] = v.x; f[4 * j2 + 1] = v.y; f[4 * j2 + 2] = v.z; f[4 * j2 + 3] = v.w;
        }
        #pragma unroll
        for (int tt = 0; tt < 16; ++tt) {
            const float dx = qx - f[3 * tt], dy = qy - f[3 * tt + 1], dz = qz - f[3 * tt + 2];
            const float d  = fmaf(dx, dx, fmaf(dy, dy, dz * dz));   // exact, >= 0
            const unsigned int pk = (__float_as_uint(d) & 0xFFFFFF80u)
                                  | (unsigned int)(c * 16 + tt);
            best = min(best, pk);                          // ties -> lowest local idx
        }
    }
    const int idx = gr * GRP + (int)(best & 127u);
    idxArr[g] = idx;
    atomicAdd(&cnt[bz * N + idx], 1);
}

__global__ __launch_bounds__(256) void dacl_loss(
    const float* __restrict__ gts, const float* __restrict__ preds,
    const int* __restrict__ idxArr, const int* __restrict__ cnt,
    float* __restrict__ out, int B, int N)
{
    const int bz  = blockIdx.y;
    const int dir = bz / B;
    const int b   = bz - dir * B;
    const float* __restrict__ q = (dir == 0 ? gts : preds) + (size_t)b * N * 3;
    const float* __restrict__ t = (dir == 0 ? preds : gts) + (size_t)b * N * 3;
    const size_t base = (size_t)bz * N;

    float s = 0.0f;
    for (int i = blockIdx.x * 256 + threadIdx.x; i < N; i += 32 * 256) {
        const int idx = idxArr[base + i];
        const float dx = q[3 * i]     - t[3 * idx];        // reference's gather form
        const float dy = q[3 * i + 1] - t[3 * idx + 1];
        const float dz = q[3 * i + 2] - t[3 * idx + 2];
        const float d  = dx * dx + dy * dy + dz * dz;
        const float c  = (float)cnt[base + idx];           // count^N_LAMBDA, lambda=1
        s += 1.0f - expf(-d) / (c + 1e-6f);                // frac terms = 1
    }
    for (int off = 32; off > 0; off >>= 1) s += __shfl_down(s, off, 64);
    if ((threadIdx.x & 63) == 0)
        atomicAdd(&out[b], s / (2.0f * (float)N));         // (mean1+mean2)/2
}

extern "C" void kernel_launch(void* const* d_in, const int* in_sizes, int n_in,
                              void* d_out, int out_size, void* d_ws, size_t ws_size,
                              hipStream_t stream)
{
    const float* gts   = (const float*)d_in[0];
    const float* preds = (const float*)d_in[1];

    const int N = NPTS;
    const int B = in_sizes[0] / (N * 3);                   // = 4

    const size_t nTot = (size_t)2 * B * N;                 // 65536 queries
    float* slot   = (float*)d_ws;                          // NGRP x nTot (16.8MB)
    int*   idxArr = (int*)((char*)d_ws + (size_t)NGRP * nTot * sizeof(float));
    int*   cnt    = idxArr + nTot;

    dim3 gA(QCH, NSLICE, 2 * B);                           // 64 x 4 x 8 = 2048 blocks
    dacl_partial<<<gA, BLK, 0, stream>>>(gts, preds, slot, cnt, B, N);

    dacl_merge<<<(int)(nTot / 256), 256, 0, stream>>>(
        gts, preds, slot, idxArr, cnt, (float*)d_out, out_size, B, N);

    dim3 gC(32, 2 * B);
    dacl_loss<<<gC, 256, 0, stream>>>(gts, preds, idxArr, cnt, (float*)d_out, B, N);
}